// Round 4
// baseline (272.274 us; speedup 1.0000x reference)
//
#include <hip/hip_runtime.h>
#include <hip/hip_bf16.h>
#include <hip/hip_cooperative_groups.h>

namespace cg = cooperative_groups;

#define BATCH 8
#define CIN 1024
#define HW2 9216
#define COUT 256
#define NSH 4
#define RHID 64
#define CPG 8
#define EPSV 1e-5f
#define GRPSZ (CPG * HW2)   // 73728 elements per (b, group)

typedef __attribute__((ext_vector_type(8))) short bf16x8;
typedef __attribute__((ext_vector_type(4))) float f32x4;

__device__ __forceinline__ unsigned short f2bf(float f) {
  unsigned u = __builtin_bit_cast(unsigned, f);
  u = (u + 0x7fffu + ((u >> 16) & 1u)) >> 16;
  return (unsigned short)u;
}

// ---------------- kernel 1: global average pool (row sums) ------------------
__global__ __launch_bounds__(256) void k_pool(
    const float* __restrict__ feat, float* __restrict__ pooled) {
  int row = blockIdx.x;            // 8192 = b*CIN + c
  const float* base = feat + (size_t)row * HW2;
  float s = 0.f;
  #pragma unroll
  for (int i = 0; i < 9; ++i) {
    float4 v = *(const float4*)(base + (size_t)(i * 256 + threadIdx.x) * 4);
    s += v.x + v.y + v.z + v.w;
  }
  #pragma unroll
  for (int off = 32; off > 0; off >>= 1) s += __shfl_down(s, off);
  __shared__ float ls[4];
  if ((threadIdx.x & 63) == 0) ls[threadIdx.x >> 6] = s;
  __syncthreads();
  if (threadIdx.x == 0) pooled[row] = ls[0] + ls[1] + ls[2] + ls[3];
}

// ---------------- kernel 2a: SE mlp -> s[b][4] ------------------------------
__global__ __launch_bounds__(256) void k_se(
    const float* __restrict__ pooled, const float* __restrict__ w1,
    const float* __restrict__ b1, const float* __restrict__ w2,
    const float* __restrict__ b2, float* __restrict__ sg) {
  int b = blockIdx.x;
  int r = threadIdx.x & 63, q = threadIdx.x >> 6;
  const float* pp = pooled + b * CIN + q * 256;
  const float* wrow = w1 + (size_t)r * CIN + q * 256;
  float acc = 0.f;
  for (int c = 0; c < 256; ++c) acc += pp[c] * wrow[c];
  __shared__ float part[4][64];
  __shared__ float hid[64];
  part[q][r] = acc;
  __syncthreads();
  if (q == 0) {
    float h = (part[0][r] + part[1][r] + part[2][r] + part[3][r]) *
                  (1.f / (float)HW2) + b1[r];
    hid[r] = h > 0.f ? h : 0.f;
  }
  __syncthreads();
  if (threadIdx.x < NSH) {
    float a = 0.f;
    for (int k = 0; k < RHID; ++k) a += hid[k] * w2[threadIdx.x * RHID + k];
    a += b2[threadIdx.x];
    sg[b * NSH + threadIdx.x] = 1.f / (1.f + expf(-a));
  }
}

// -------- kernel 2b: conv_weight -> bf16; also zeroes stpart ----------------
__global__ __launch_bounds__(256) void k_cw(
    const float* __restrict__ w_red, const float* __restrict__ sg,
    unsigned short* __restrict__ cw, float* __restrict__ stpart) {
  if (blockIdx.x == 0) {
    stpart[threadIdx.x] = 0.f;
    stpart[256 + threadIdx.x] = 0.f;
  }
  int e4 = (blockIdx.x * 256 + threadIdx.x) * 4;   // < 8*256*1024
  int b = e4 >> 18;
  int rem = e4 & 262143;
  int i = rem & 1023;
  float sv = sg[b * NSH + (i >> 8)];
  float4 v = *(const float4*)(w_red + rem);
  ushort4 o;
  o.x = f2bf(v.x * sv); o.y = f2bf(v.y * sv);
  o.z = f2bf(v.z * sv); o.w = f2bf(v.w * sv);
  *(ushort4*)(cw + e4) = o;
}

// ---------------- kernel 3: cooperative fused GEMM + GN + ReLU --------------
// BM=256, BN=288, BK=32. grid = 32 x 8 = 256 blocks (1/CU), 512 thr (8 waves,
// 4M x 2N; wave tile 64x144 = 4x9 frags). 2-phase LDS double-buffer.
__device__ __forceinline__ void gl16(const void* g, void* l) {
  __builtin_amdgcn_global_load_lds(
      (const __attribute__((address_space(1))) unsigned int*)g,
      (__attribute__((address_space(3))) unsigned int*)l, 16, 0, 0);
}

__global__ __launch_bounds__(512, 2) void k_coop(
    const float* __restrict__ feat, const unsigned short* __restrict__ cw,
    float* __restrict__ out, float* __restrict__ stpart,
    const float* __restrict__ gamma, const float* __restrict__ beta) {
  __shared__ unsigned short As[2][256 * 32];   // 32 KB (dbuf)
  __shared__ unsigned short Bs[2][288 * 32];   // 36 KB (dbuf), [n][k] XOR-swz
  const int nt = blockIdx.x, b = blockIdx.y;
  const int p0 = nt * 288;
  const int tid = threadIdx.x;
  const int lane = tid & 63, w = tid >> 6;
  const int wr = w >> 1, wc = w & 1;
  const int key = (lane & 3) ^ ((lane >> 2) & 3);   // read-side chunk swizzle
  const unsigned short* cwb = cw + (size_t)b * COUT * CIN;
  const float* fbb = feat + (size_t)b * CIN * HW2;
  float* ob = out + (size_t)b * COUT * HW2;

  // A staging decode: chunk t = q*512+tid; row=t>>2; LDS chunk (t&3) holds
  // global chunk (t&3)^key(row), key(row)=(row&3)^((row>>2)&3)  [m173 pattern]
  int asrc[2];
  #pragma unroll
  for (int q = 0; q < 2; ++q) {
    int t = q * 512 + tid;
    int row = t >> 2;
    int gch = (t & 3) ^ ((row & 3) ^ ((row >> 2) & 3));
    asrc[q] = row * CIN + gch * 8;
  }
  // B task decode: 1152 tasks (288 n x 4 kblk); threads 384..511 take a 3rd
  const int ntask = (tid >= 384) ? 3 : 2;
  int tkb[3], tn[3], tws[3];
  #pragma unroll
  for (int i = 0; i < 3; ++i) {
    int task = (i == 0) ? tid : (i == 1) ? tid + 512 : tid + 640;
    int t5 = task >> 5;
    int kb = (t5 * 57) >> 9;            // t5/9, valid t5<37
    int n = task - kb * 288;
    int swz = (n & 3) ^ ((n >> 2) & 3);
    tkb[i] = kb; tn[i] = n;
    tws[i] = n * 32 + ((kb ^ swz) * 8);
  }

  f32x4 acc[4][9] = {};

  // ---- prologue: stage k-step 0 into buffer 0 ----
  {
    #pragma unroll
    for (int q = 0; q < 2; ++q)
      gl16(cwb + asrc[q], &As[0][(q * 512 + w * 64) * 8]);
    float bv[3][8];
    #pragma unroll
    for (int i = 0; i < 3; ++i) if (i < ntask) {
      const float* s = fbb + (size_t)(tkb[i] * 8) * HW2 + p0 + tn[i];
      #pragma unroll
      for (int j = 0; j < 8; ++j) bv[i][j] = s[(size_t)j * HW2];
    }
    #pragma unroll
    for (int i = 0; i < 3; ++i) if (i < ntask) {
      bf16x8 pk;
      #pragma unroll
      for (int j = 0; j < 8; ++j) pk[j] = (short)f2bf(bv[i][j]);
      *(bf16x8*)&Bs[0][tws[i]] = pk;
    }
  }

  // ---- main loop: one barrier per k-step, 2-phase dbuf ----
  for (int kk = 0; kk < 32; ++kk) {
    const int cur = kk & 1, nx = cur ^ 1;
    __syncthreads();   // buf[cur] ready; prev readers of buf[nx] drained
    float bv[3][8];
    if (kk < 31) {
      const int k0n = (kk + 1) * 32;
      #pragma unroll
      for (int q = 0; q < 2; ++q)
        gl16(cwb + asrc[q] + k0n, &As[nx][(q * 512 + w * 64) * 8]);
      #pragma unroll
      for (int i = 0; i < 3; ++i) if (i < ntask) {
        const float* s = fbb + (size_t)(k0n + tkb[i] * 8) * HW2 + p0 + tn[i];
        #pragma unroll
        for (int j = 0; j < 8; ++j) bv[i][j] = s[(size_t)j * HW2];
      }
    }
    const unsigned short* Ac = As[cur];
    const unsigned short* Bc = Bs[cur];
    bf16x8 af[4];
    #pragma unroll
    for (int mi = 0; mi < 4; ++mi) {
      int row = wr * 64 + mi * 16 + (lane & 15);
      af[mi] = *(const bf16x8*)&Ac[row * 32 + (((lane >> 4) ^ key) * 8)];
    }
    #pragma unroll
    for (int ni = 0; ni < 9; ++ni) {
      int n = wc * 144 + ni * 16 + (lane & 15);
      bf16x8 bfv = *(const bf16x8*)&Bc[n * 32 + (((lane >> 4) ^ key) * 8)];
      #pragma unroll
      for (int mi = 0; mi < 4; ++mi)
        acc[mi][ni] = __builtin_amdgcn_mfma_f32_16x16x32_bf16(
            af[mi], bfv, acc[mi][ni], 0, 0, 0);
    }
    if (kk < 31) {   // write-late: loads had the MFMA block to land
      #pragma unroll
      for (int i = 0; i < 3; ++i) if (i < ntask) {
        bf16x8 pk;
        #pragma unroll
        for (int j = 0; j < 8; ++j) pk[j] = (short)f2bf(bv[i][j]);
        *(bf16x8*)&Bs[nx][tws[i]] = pk;
      }
    }
  }

  // ---- fused GN partial stats (rows of (wr,mi,lane-half) share one group) --
  #pragma unroll
  for (int mi = 0; mi < 4; ++mi) {
    float s1 = 0.f, s2 = 0.f;
    #pragma unroll
    for (int ni = 0; ni < 9; ++ni)
      #pragma unroll
      for (int j = 0; j < 4; ++j) {
        float v = acc[mi][ni][j];
        s1 += v; s2 += v * v;
      }
    #pragma unroll
    for (int off = 1; off <= 16; off <<= 1) {
      s1 += __shfl_xor(s1, off);
      s2 += __shfl_xor(s2, off);
    }
    if ((lane & 31) == 0) {
      int g = 8 * wr + 2 * mi + (lane >> 5);
      atomicAdd(&stpart[(b * 32 + g) * 2], s1);
      atomicAdd(&stpart[(b * 32 + g) * 2 + 1], s2);
    }
  }

  __threadfence();
  cg::this_grid().sync();

  // ---- finalize stats + apply GN + ReLU straight from registers ----
  const float inv = 1.f / (float)GRPSZ;
  #pragma unroll
  for (int mi = 0; mi < 4; ++mi) {
    int g = 8 * wr + 2 * mi + (lane >> 5);
    float s1 = stpart[(b * 32 + g) * 2];
    float s2 = stpart[(b * 32 + g) * 2 + 1];
    float mu = s1 * inv;
    float rsq = rsqrtf(fmaxf(s2 * inv - mu * mu, 0.f) + EPSV);
    int r0 = wr * 64 + mi * 16 + ((lane >> 4) << 2);
    float4 g4 = *(const float4*)&gamma[r0];
    float4 b4 = *(const float4*)&beta[r0];
    float sc[4], bi[4];
    sc[0] = g4.x * rsq; bi[0] = b4.x - mu * sc[0];
    sc[1] = g4.y * rsq; bi[1] = b4.y - mu * sc[1];
    sc[2] = g4.z * rsq; bi[2] = b4.z - mu * sc[2];
    sc[3] = g4.w * rsq; bi[3] = b4.w - mu * sc[3];
    #pragma unroll
    for (int ni = 0; ni < 9; ++ni) {
      int p = p0 + wc * 144 + ni * 16 + (lane & 15);
      #pragma unroll
      for (int j = 0; j < 4; ++j) {
        float v = acc[mi][ni][j] * sc[j] + bi[j];
        ob[(size_t)(r0 + j) * HW2 + p] = fmaxf(v, 0.f);
      }
    }
  }
}

extern "C" void kernel_launch(void* const* d_in, const int* in_sizes, int n_in,
                              void* d_out, int out_size, void* d_ws, size_t ws_size,
                              hipStream_t stream) {
  const float* feat  = (const float*)d_in[0];
  const float* w1    = (const float*)d_in[1];
  const float* b1    = (const float*)d_in[2];
  const float* w2    = (const float*)d_in[3];
  const float* b2    = (const float*)d_in[4];
  const float* w_red = (const float*)d_in[5];
  const float* gamma = (const float*)d_in[6];
  const float* beta  = (const float*)d_in[7];
  float* out = (float*)d_out;

  char* ws = (char*)d_ws;
  unsigned short* cw = (unsigned short*)ws;            //  4,194,304 B
  float* pooled = (float*)(ws + 4194304);              //     32,768 B
  float* sg     = (float*)(ws + 4227072);              //        128 B
  float* stpart = (float*)(ws + 4227200);              //      2,048 B
  // total ws need: ~4.3 MB

  k_pool<<<8192, 256, 0, stream>>>(feat, pooled);
  k_se<<<8, 256, 0, stream>>>(pooled, w1, b1, w2, b2, sg);
  k_cw<<<2048, 256, 0, stream>>>(w_red, sg, cw, stpart);
  void* kargs[] = {(void*)&feat, (void*)&cw, (void*)&out,
                   (void*)&stpart, (void*)&gamma, (void*)&beta};
  hipLaunchCooperativeKernel(reinterpret_cast<void*>(k_coop), dim3(32, 8),
                             dim3(512), kargs, 0, stream);
}

// Round 6
// 245.087 us; speedup vs baseline: 1.1109x; 1.1109x over previous
//
#include <hip/hip_runtime.h>
#include <hip/hip_bf16.h>

#define CIN 1024
#define HW2 9216
#define COUT 256
#define NSH 4
#define RHID 64
#define CPG 8
#define EPSV 1e-5f
#define GRPSZ (CPG * HW2)

typedef __attribute__((ext_vector_type(8))) short bf16x8;
typedef __attribute__((ext_vector_type(4))) float f32x4;

__device__ __forceinline__ unsigned short f2bf(float f) {
  unsigned u = __builtin_bit_cast(unsigned, f);
  u = (u + 0x7fffu + ((u >> 16) & 1u)) >> 16;
  return (unsigned short)u;
}
__device__ __forceinline__ float bf2f(unsigned short h) {
  unsigned u = (unsigned)h << 16;
  return __builtin_bit_cast(float, u);
}

// ---- kernel 1: feat -> bf16 GEMM panels + GAP row sums ---------------------
// Panel layout (n-major, k-minor, chunk-XOR pre-swizzled in GLOBAL):
//   elem(b,kq,np,n,k=c*8+j) at ((b*32+kq)*576+np)*512 + n*32 + (c^(n&3))*8 + j
// A GEMM k-step (kq) for tile nt stages panels np=nt*8..+8 = 8KB contiguous.
// block (seg<4, kq<32, b<8): rows kq*32..+32, cols seg*2304..+2304.
__global__ __launch_bounds__(256) void k_prep(
    const float* __restrict__ feat, unsigned short* __restrict__ fbp,
    float* __restrict__ pooled) {
  __shared__ unsigned short T[32][260];   // pad: row stride 520B (8B-aligned)
  const int seg = blockIdx.x, kq = blockIdx.y, b = blockIdx.z;
  const int tid = threadIdx.x, lane = tid & 63, w = tid >> 6;
  const float* f0 = feat + ((size_t)(b * CIN + kq * 32)) * HW2 + seg * 2304;
  unsigned short* dbase = fbp + ((size_t)(b * 32 + kq) * 576 + seg * 144) * 512;
  float rs[8];
  #pragma unroll
  for (int i = 0; i < 8; ++i) rs[i] = 0.f;

  for (int it = 0; it < 9; ++it) {
    __syncthreads();   // previous gather phase done with T
    #pragma unroll
    for (int i = 0; i < 8; ++i) {        // load [32k][256n] tile, coalesced
      int r = w * 8 + i;
      float4 v = *(const float4*)(f0 + (size_t)r * HW2 + it * 256 + lane * 4);
      rs[i] += v.x + v.y + v.z + v.w;
      ushort4 o;
      o.x = f2bf(v.x); o.y = f2bf(v.y); o.z = f2bf(v.z); o.w = f2bf(v.w);
      *(ushort4*)&T[r][lane * 4] = o;
    }
    __syncthreads();
    // gather: chunk u = (pl<4b? no: pl=u>>6, n=(u>>2)&15, c=u&3); 16 panels/it
    #pragma unroll
    for (int i = 0; i < 4; ++i) {
      int u = i * 256 + tid;             // wave w, iter i -> panel pl = i*4+w
      int pl = u >> 6, n = (u >> 2) & 15, c = u & 3;
      int col = pl * 16 + n;
      bf16x8 pk;
      #pragma unroll
      for (int j = 0; j < 8; ++j) pk[j] = (short)T[c * 8 + j][col];
      *(bf16x8*)(dbase + ((size_t)(it * 16 + pl)) * 512 + n * 32 +
                 ((c ^ (n & 3)) * 8)) = pk;
    }
  }
  // GAP partial sums: row r = w*8+i is cin row kq*32 + r
  #pragma unroll
  for (int i = 0; i < 8; ++i) {
    float s = rs[i];
    #pragma unroll
    for (int off = 32; off > 0; off >>= 1) s += __shfl_down(s, off);
    if (lane == 0) atomicAdd(&pooled[b * CIN + kq * 32 + w * 8 + i], s);
  }
}

// ---- kernel 2a: SE mlp -> s[b][4] ------------------------------------------
__global__ __launch_bounds__(256) void k_se(
    const float* __restrict__ pooled, const float* __restrict__ w1,
    const float* __restrict__ b1, const float* __restrict__ w2,
    const float* __restrict__ b2, float* __restrict__ sg) {
  int b = blockIdx.x;
  int r = threadIdx.x & 63, q = threadIdx.x >> 6;
  const float* pp = pooled + b * CIN + q * 256;
  const float* wrow = w1 + (size_t)r * CIN + q * 256;
  float acc = 0.f;
  for (int c = 0; c < 256; ++c) acc += pp[c] * wrow[c];
  __shared__ float part[4][64];
  __shared__ float hid[64];
  part[q][r] = acc;
  __syncthreads();
  if (q == 0) {
    float h = (part[0][r] + part[1][r] + part[2][r] + part[3][r]) *
                  (1.f / (float)HW2) + b1[r];
    hid[r] = h > 0.f ? h : 0.f;
  }
  __syncthreads();
  if (threadIdx.x < NSH) {
    float a = 0.f;
    for (int k = 0; k < RHID; ++k) a += hid[k] * w2[threadIdx.x * RHID + k];
    a += b2[threadIdx.x];
    sg[b * NSH + threadIdx.x] = 1.f / (1.f + expf(-a));
  }
}

// ---- kernel 2b: conv_weight -> bf16; also zeroes stpart --------------------
__global__ __launch_bounds__(256) void k_cw(
    const float* __restrict__ w_red, const float* __restrict__ sg,
    unsigned short* __restrict__ cw, float* __restrict__ stpart) {
  if (blockIdx.x == 0) {
    stpart[threadIdx.x] = 0.f;
    stpart[256 + threadIdx.x] = 0.f;
  }
  int e4 = (blockIdx.x * 256 + threadIdx.x) * 4;
  int b = e4 >> 18;
  int rem = e4 & 262143;
  int i = rem & 1023;
  float sv = sg[b * NSH + (i >> 8)];
  float4 v = *(const float4*)(w_red + rem);
  ushort4 o;
  o.x = f2bf(v.x * sv); o.y = f2bf(v.y * sv);
  o.z = f2bf(v.z * sv); o.w = f2bf(v.w * sv);
  *(ushort4*)(cw + e4) = o;
}

// ---- kernel 3: batched GEMM (m97 2-barrier, all-gl16) + fused stats --------
// BM=256, BN=128, BK=32; 512 thr = 8 waves (4M x 2N), wave tile 64x64.
__device__ __forceinline__ void gl16(const void* g, void* l) {
  __builtin_amdgcn_global_load_lds(
      (const __attribute__((address_space(1))) unsigned int*)g,
      (__attribute__((address_space(3))) unsigned int*)l, 16, 0, 0);
}

__global__ __launch_bounds__(512, 4) void k_gemm(
    const unsigned short* __restrict__ fbp, const unsigned short* __restrict__ cw,
    unsigned short* __restrict__ xb, float* __restrict__ stpart) {
  __shared__ unsigned short As[256 * 32];  // [m][32k] linear
  __shared__ unsigned short Bs[128 * 32];  // 8 panels, pre-swizzled in global
  const int nt = blockIdx.x, b = blockIdx.y;
  const int p0 = nt * 128;
  const int tid = threadIdx.x, lane = tid & 63, w = tid >> 6;
  const int wr = w >> 1, wc = w & 1;
  const unsigned short* cwb = cw + (size_t)b * COUT * CIN;
  const unsigned short* bsrc = fbp + ((size_t)(b * 32) * 576 + nt * 8) * 512 +
                               tid * 8;

  f32x4 acc[4][4] = {};

  for (int kq = 0; kq < 32; ++kq) {
    __syncthreads();
    #pragma unroll
    for (int q = 0; q < 2; ++q) {        // A: 256x32 bf16 = 16KB, linear
      int t = q * 512 + tid;
      gl16(cwb + (t >> 2) * CIN + kq * 32 + (t & 3) * 8,
           &As[(q * 512 + w * 64) * 8]);
    }
    gl16(bsrc + (size_t)kq * 294912, &Bs[(w * 64) * 8]);  // B: 8KB contiguous
    __syncthreads();

    bf16x8 af[4];
    #pragma unroll
    for (int mi = 0; mi < 4; ++mi) {
      int row = wr * 64 + mi * 16 + (lane & 15);
      af[mi] = *(const bf16x8*)&As[row * 32 + (lane >> 4) * 8];
    }
    bf16x8 bfv[4];
    #pragma unroll
    for (int ni = 0; ni < 4; ++ni) {
      int n = wc * 64 + ni * 16 + (lane & 15);
      bfv[ni] = *(const bf16x8*)&Bs[n * 32 + (((lane >> 4) ^ (n & 3)) * 8)];
    }
    #pragma unroll
    for (int mi = 0; mi < 4; ++mi)
      #pragma unroll
      for (int ni = 0; ni < 4; ++ni)
        acc[mi][ni] = __builtin_amdgcn_mfma_f32_16x16x32_bf16(
            af[mi], bfv[ni], acc[mi][ni], 0, 0, 0);
  }

  // ---- C-write (bf16): col = lane&15, row = (lane>>4)*4 + j ----
  unsigned short* ob = xb + (size_t)b * COUT * HW2;
  #pragma unroll
  for (int mi = 0; mi < 4; ++mi) {
    int r0 = wr * 64 + mi * 16 + ((lane >> 4) << 2);
    #pragma unroll
    for (int ni = 0; ni < 4; ++ni) {
      int p = p0 + wc * 64 + ni * 16 + (lane & 15);
      #pragma unroll
      for (int j = 0; j < 4; ++j)
        ob[(size_t)(r0 + j) * HW2 + p] = f2bf(acc[mi][ni][j]);
    }
  }

  // ---- fused GN partial stats: g = 8*wr + 2*mi + (lane>=32) ----
  #pragma unroll
  for (int mi = 0; mi < 4; ++mi) {
    float s1 = 0.f, s2 = 0.f;
    #pragma unroll
    for (int ni = 0; ni < 4; ++ni)
      #pragma unroll
      for (int j = 0; j < 4; ++j) {
        float v = acc[mi][ni][j];
        s1 += v; s2 += v * v;
      }
    #pragma unroll
    for (int off = 1; off <= 16; off <<= 1) {
      s1 += __shfl_xor(s1, off);
      s2 += __shfl_xor(s2, off);
    }
    if ((lane & 31) == 0) {
      int g = 8 * wr + 2 * mi + (lane >> 5);
      atomicAdd(&stpart[(b * 32 + g) * 2], s1);
      atomicAdd(&stpart[(b * 32 + g) * 2 + 1], s2);
    }
  }
}

// ---- kernel 4: finalize stats ----------------------------------------------
__global__ __launch_bounds__(256) void k_fin(const float* __restrict__ stpart,
                                             float2* __restrict__ st) {
  int bg = threadIdx.x;
  float s1 = stpart[bg * 2], s2 = stpart[bg * 2 + 1];
  const float inv = 1.f / (float)GRPSZ;
  float mu = s1 * inv;
  float var = s2 * inv - mu * mu;
  st[bg] = make_float2(mu, rsqrtf(var + EPSV));
}

// ---- kernel 5: GN apply + ReLU (bf16 x -> fp32 out) ------------------------
__global__ __launch_bounds__(256) void k_apply(
    const unsigned short* __restrict__ xb, float* __restrict__ out,
    const float2* __restrict__ st, const float* __restrict__ gamma,
    const float* __restrict__ beta) {
  #pragma unroll
  for (int i = 0; i < 4; ++i) {
    unsigned e = ((unsigned)blockIdx.x * 1024 + i * 256 + threadIdx.x) * 4;
    unsigned row = (e >> 10) / 9;   // e / 9216
    int o = row & 255;
    float2 s = st[row >> 3];
    float g = gamma[o] * s.y;
    float bb = beta[o] - s.x * g;
    ushort4 v = *(const ushort4*)(xb + e);
    float4 r;
    r.x = fmaxf(bf2f(v.x) * g + bb, 0.f);
    r.y = fmaxf(bf2f(v.y) * g + bb, 0.f);
    r.z = fmaxf(bf2f(v.z) * g + bb, 0.f);
    r.w = fmaxf(bf2f(v.w) * g + bb, 0.f);
    *(float4*)(out + e) = r;
  }
}

extern "C" void kernel_launch(void* const* d_in, const int* in_sizes, int n_in,
                              void* d_out, int out_size, void* d_ws, size_t ws_size,
                              hipStream_t stream) {
  const float* feat  = (const float*)d_in[0];
  const float* w1    = (const float*)d_in[1];
  const float* b1    = (const float*)d_in[2];
  const float* w2    = (const float*)d_in[3];
  const float* b2    = (const float*)d_in[4];
  const float* w_red = (const float*)d_in[5];
  const float* gamma = (const float*)d_in[6];
  const float* beta  = (const float*)d_in[7];
  float* out = (float*)d_out;

  char* ws = (char*)d_ws;
  unsigned short* fbp = (unsigned short*)ws;               // 150,994,944 B
  unsigned short* cw  = (unsigned short*)(ws + 150994944); //   4,194,304 B
  unsigned short* xbb = (unsigned short*)(ws + 155189248); //  37,748,736 B
  float* pooled = (float*)(ws + 192937984);                //      32,768 B
  float* sg     = (float*)(ws + 192970752);                //         128 B
  float* stpart = (float*)(ws + 192970880);                //       2,048 B
  float2* st    = (float2*)(ws + 192972928);               //       2,048 B

  hipMemsetAsync(pooled, 0, 8192 * sizeof(float), stream);
  k_prep<<<dim3(4, 32, 8), 256, 0, stream>>>(feat, fbp, pooled);
  k_se<<<8, 256, 0, stream>>>(pooled, w1, b1, w2, b2, sg);
  k_cw<<<2048, 256, 0, stream>>>(w_red, sg, cw, stpart);
  k_gemm<<<dim3(72, 8), 512, 0, stream>>>(fbp, cw, xbb, stpart);
  k_fin<<<1, 256, 0, stream>>>(stpart, st);
  k_apply<<<4608, 256, 0, stream>>>(xbb, out, st, gamma, beta);
}